// Round 1
// baseline (458.874 us; speedup 1.0000x reference)
//
#include <hip/hip_runtime.h>

typedef unsigned short u16;
typedef unsigned int uint;
typedef __attribute__((ext_vector_type(8))) short bf16x8;
typedef __attribute__((ext_vector_type(4))) float f32x4;

#define NBATCH 16
#define SDIM   1024
#define INDIM  512
#define OUTDIM 512
#define HEADS  8
#define DHEAD  64
#define MROWS  (NBATCH * SDIM)   // 16384
#define KDIM   512

__device__ __forceinline__ u16 f2bf(float f) {
  union { float f; uint u; } v; v.f = f;
  uint u = v.u;
  return (u16)((u + 0x7FFFu + ((u >> 16) & 1u)) >> 16);  // RNE
}

__device__ __forceinline__ void gload16(const void* g, void* l) {
  __builtin_amdgcn_global_load_lds(
      (const __attribute__((address_space(1))) uint*)g,
      (__attribute__((address_space(3))) uint*)l, 16, 0, 0);
}

// ---------------------------------------------------------------- prep
__global__ __launch_bounds__(256) void prep_kernel(
    const float* __restrict__ x, const float* __restrict__ wq,
    const float* __restrict__ wk, const float* __restrict__ wv,
    const float* __restrict__ w_out,
    u16* __restrict__ xb, u16* __restrict__ W1T, u16* __restrict__ W2T) {
  int gid = blockIdx.x * blockDim.x + threadIdx.x;
  int stride = gridDim.x * blockDim.x;
  const int NX4 = MROWS * INDIM / 4;
  for (int i = gid; i < NX4; i += stride) {
    float4 v = ((const float4*)x)[i];
    ((ushort4*)xb)[i] = make_ushort4(f2bf(v.x), f2bf(v.y), f2bf(v.z), f2bf(v.w));
  }
  // W1T[n][f], n = proj*512 + h*64 + d ; wq scaled by 1/sqrt(DH)=0.125 (exact)
  for (int i = gid; i < 3 * OUTDIM * INDIM; i += stride) {
    int n = i >> 9, f = i & 511;
    int proj = n >> 9, hd = n & 511, h = hd >> 6, d = hd & 63;
    const float* src = (proj == 0) ? wq : (proj == 1) ? wk : wv;
    float val = src[(h * INDIM + f) * DHEAD + d];
    if (proj == 0) val *= 0.125f;
    W1T[i] = f2bf(val);
  }
  // W2T[n][f] = w_out[f][n]
  for (int i = gid; i < OUTDIM * INDIM; i += stride) {
    int n = i >> 9, f = i & 511;
    W2T[i] = f2bf(w_out[f * OUTDIM + n]);
  }
}

// ---------------------------------------------------------------- GEMM 128x128, BK=32
// A: [M][512] bf16 row-major. Bt: [N][512] bf16 (B transposed, k contiguous).
// EPI 0: QKV scatter epilogue. EPI 1: fp32 Y store.
template <int EPI>
__global__ __launch_bounds__(256) void gemm128(
    const u16* __restrict__ A, const u16* __restrict__ Bt,
    u16* __restrict__ Qb, u16* __restrict__ Kb, u16* __restrict__ VTb,
    float* __restrict__ Y) {
  __shared__ u16 As[128 * 32];
  __shared__ u16 Bs[128 * 32];
  const int tid = threadIdx.x;
  const int w = tid >> 6, lane = tid & 63;
  const int quad = lane >> 4, ln = lane & 15;
  const int wm = w >> 1, wn = w & 1;
  const int m0 = blockIdx.y * 128, n0 = blockIdx.x * 128;

  f32x4 zero4 = {0.f, 0.f, 0.f, 0.f};
  f32x4 acc[4][4];
  for (int i = 0; i < 4; i++)
    for (int j = 0; j < 4; j++) acc[i][j] = zero4;

  const char* Ag = (const char*)(A + (size_t)m0 * KDIM);
  const char* Bg = (const char*)(Bt + (size_t)n0 * KDIM);
  const int r0 = w * 16 + (lane >> 2);   // row within first 64
  const int cb = (lane & 3) * 16;        // col byte within 64B row-slice

  for (int kk = 0; kk < KDIM; kk += 32) {
    __syncthreads();
    gload16(Ag + (size_t)r0 * (KDIM * 2) + kk * 2 + cb, (char*)As + w * 1024);
    gload16(Ag + (size_t)(r0 + 64) * (KDIM * 2) + kk * 2 + cb, (char*)As + 4096 + w * 1024);
    gload16(Bg + (size_t)r0 * (KDIM * 2) + kk * 2 + cb, (char*)Bs + w * 1024);
    gload16(Bg + (size_t)(r0 + 64) * (KDIM * 2) + kk * 2 + cb, (char*)Bs + 4096 + w * 1024);
    __syncthreads();
    bf16x8 af[4], bfr[4];
    for (int mt = 0; mt < 4; mt++)
      af[mt] = *(const bf16x8*)&As[(wm * 64 + mt * 16 + ln) * 32 + quad * 8];
    for (int nt = 0; nt < 4; nt++)
      bfr[nt] = *(const bf16x8*)&Bs[(wn * 64 + nt * 16 + ln) * 32 + quad * 8];
    for (int mt = 0; mt < 4; mt++)
      for (int nt = 0; nt < 4; nt++)
        acc[mt][nt] = __builtin_amdgcn_mfma_f32_16x16x32_bf16(af[mt], bfr[nt], acc[mt][nt], 0, 0, 0);
  }

  for (int mt = 0; mt < 4; mt++) {
    int mbase = m0 + wm * 64 + mt * 16 + quad * 4;   // 4 consecutive rows r=0..3
    int b = mbase >> 10, sbase = mbase & 1023;       // rows never cross batch (align 4)
    for (int nt = 0; nt < 4; nt++) {
      f32x4 c = acc[mt][nt];
      int col = n0 + wn * 64 + nt * 16 + ln;
      if (EPI == 0) {
        int proj = n0 >> 9;  // uniform per block (512 % 128 == 0)
        int hd = col & 511, h = hd >> 6, d = hd & 63;
        if (proj == 2) {
          // V transposed: VT[h][b][d][s], 4 consecutive s -> one 8B store
          *(ushort4*)&VTb[((size_t)(h * 16 + b) * 64 + d) * 1024 + sbase] =
              make_ushort4(f2bf(c[0]), f2bf(c[1]), f2bf(c[2]), f2bf(c[3]));
        } else {
          u16* dst = (proj == 0) ? Qb : Kb;   // [h][b][s][d]
          size_t base = ((size_t)(h * 16 + b) * 1024) * 64 + d;
          dst[base + (size_t)(sbase + 0) * 64] = f2bf(c[0]);
          dst[base + (size_t)(sbase + 1) * 64] = f2bf(c[1]);
          dst[base + (size_t)(sbase + 2) * 64] = f2bf(c[2]);
          dst[base + (size_t)(sbase + 3) * 64] = f2bf(c[3]);
        }
      } else {
        Y[(size_t)(mbase + 0) * OUTDIM + col] = c[0];
        Y[(size_t)(mbase + 1) * OUTDIM + col] = c[1];
        Y[(size_t)(mbase + 2) * OUTDIM + col] = c[2];
        Y[(size_t)(mbase + 3) * OUTDIM + col] = c[3];
      }
    }
  }
}

// ---------------------------------------------------------------- attention
// grid 256 = h (bid&7, pins head to XCD) x 32 s-blocks. block 512 = 8 waves:
// wave = (bg = w&3 -> batches bg*4..bg*4+3, ssub = w>>2 -> 16-row s-subtile).
// Scores computed transposed (A=K, B=Q -> S^T row=t col=s). Softmax over the
// batch axis: exact (all 16 b resident across the 4 bg-waves), no max needed
// (|score| <~ 2). P round-trips wave-private LDS to become PV A-fragments.
__global__ __launch_bounds__(512) void attn_kernel(
    const u16* __restrict__ Qb, const u16* __restrict__ Kb,
    const u16* __restrict__ VTb, u16* __restrict__ hc) {
  __shared__ float lds_sum[2 * 4 * 16 * 36];  // [ssub][bg][s16][36 t-pad]
  __shared__ u16 lds_p[8 * 4 * 16 * 40];      // [wave][bi][s16][40 t-pad]
  const int tid = threadIdx.x;
  const int w = tid >> 6, lane = tid & 63;
  const int quad = lane >> 4, ln = lane & 15;
  const int bg = w & 3, ssub = w >> 2;
  const int h = blockIdx.x & 7, sblk = blockIdx.x >> 3;
  const int s0 = sblk * 32 + ssub * 16;

  f32x4 zero4 = {0.f, 0.f, 0.f, 0.f};

  // resident Q fragments (B-operand: B[k=d][n=s], lane: s=ln, d=quad*8+j)
  bf16x8 qf[4][2];
  for (int bi = 0; bi < 4; bi++) {
    int b = bg * 4 + bi;
    const u16* Qp = Qb + ((size_t)(h * 16 + b) * 1024 + s0 + ln) * 64;
    qf[bi][0] = *(const bf16x8*)&Qp[quad * 8];
    qf[bi][1] = *(const bf16x8*)&Qp[32 + quad * 8];
  }

  f32x4 o[4][4];
  for (int i = 0; i < 4; i++)
    for (int j = 0; j < 4; j++) o[i][j] = zero4;

  for (int it = 0; it < 32; it++) {
    const int t0g = it * 32;
    f32x4 e[4][2];  // exp(scores), elements at (t = tsub*16+quad*4+r, s = ln)
    for (int bi = 0; bi < 4; bi++) {
      int b = bg * 4 + bi;
      const u16* Kp = Kb + (size_t)(h * 16 + b) * 1024 * 64;
      for (int tsub = 0; tsub < 2; tsub++) {
        f32x4 c = zero4;
        const u16* Krow = Kp + (size_t)(t0g + tsub * 16 + ln) * 64;
        c = __builtin_amdgcn_mfma_f32_16x16x32_bf16(*(const bf16x8*)&Krow[quad * 8], qf[bi][0], c, 0, 0, 0);
        c = __builtin_amdgcn_mfma_f32_16x16x32_bf16(*(const bf16x8*)&Krow[32 + quad * 8], qf[bi][1], c, 0, 0, 0);
        f32x4 ee;
        ee[0] = __expf(c[0]); ee[1] = __expf(c[1]);
        ee[2] = __expf(c[2]); ee[3] = __expf(c[3]);
        e[bi][tsub] = ee;
      }
    }
    // local (4-batch) sum, exchange across the 4 bg-waves of this s-subtile
    f32x4 ls0 = e[0][0] + e[1][0] + e[2][0] + e[3][0];
    f32x4 ls1 = e[0][1] + e[1][1] + e[2][1] + e[3][1];
    {
      float* sb = &lds_sum[((ssub * 4 + bg) * 16 + ln) * 36];
      *(f32x4*)&sb[quad * 4] = ls0;
      *(f32x4*)&sb[16 + quad * 4] = ls1;
    }
    __syncthreads();
    f32x4 L0 = zero4, L1 = zero4;
    for (int ob = 0; ob < 4; ob++) {
      const float* rb = &lds_sum[((ssub * 4 + ob) * 16 + ln) * 36];
      L0 += *(const f32x4*)&rb[quad * 4];
      L1 += *(const f32x4*)&rb[16 + quad * 4];
    }
    f32x4 R0, R1;
    for (int r = 0; r < 4; r++) {
      R0[r] = __builtin_amdgcn_rcpf(L0[r]);
      R1[r] = __builtin_amdgcn_rcpf(L1[r]);
    }
    // P = e/L -> bf16 -> wave-private LDS tile [s][t] (A-operand layout)
    for (int bi = 0; bi < 4; bi++) {
      f32x4 p0 = e[bi][0] * R0;
      f32x4 p1 = e[bi][1] * R1;
      u16* pb = &lds_p[((w * 4 + bi) * 16 + ln) * 40];
      *(ushort4*)&pb[quad * 4] = make_ushort4(f2bf(p0[0]), f2bf(p0[1]), f2bf(p0[2]), f2bf(p0[3]));
      *(ushort4*)&pb[16 + quad * 4] = make_ushort4(f2bf(p1[0]), f2bf(p1[1]), f2bf(p1[2]), f2bf(p1[3]));
    }
    __syncthreads();
    // PV: A = P[s][t] (LDS), B = V via VT[h][b][d][s] direct 16B loads
    for (int bi = 0; bi < 4; bi++) {
      int b = bg * 4 + bi;
      bf16x8 pa = *(const bf16x8*)&lds_p[((w * 4 + bi) * 16 + ln) * 40 + quad * 8];
      const u16* Vp = VTb + (size_t)(h * 16 + b) * 64 * 1024;
      for (int df = 0; df < 4; df++) {
        bf16x8 vb = *(const bf16x8*)&Vp[(size_t)(df * 16 + ln) * 1024 + t0g + quad * 8];
        o[bi][df] = __builtin_amdgcn_mfma_f32_16x16x32_bf16(pa, vb, o[bi][df], 0, 0, 0);
      }
    }
  }
  // epilogue: heads_cat [b*1024+s][h*64+d] bf16
  for (int bi = 0; bi < 4; bi++) {
    int b = bg * 4 + bi;
    for (int df = 0; df < 4; df++) {
      f32x4 c = o[bi][df];
      for (int r = 0; r < 4; r++) {
        int sg = s0 + quad * 4 + r;
        hc[((size_t)(b * 1024 + sg)) * 512 + h * 64 + df * 16 + ln] = f2bf(c[r]);
      }
    }
  }
}

// ---------------------------------------------------------------- bias + LN + LeakyReLU
__global__ __launch_bounds__(256) void ln_kernel(
    const float* __restrict__ Y, const float* __restrict__ b_out,
    const float* __restrict__ gamma, const float* __restrict__ beta,
    float* __restrict__ out) {
  const int w = threadIdx.x >> 6, lane = threadIdx.x & 63;
  const int row = blockIdx.x * 4 + w;
  const float4* yr = (const float4*)(Y + (size_t)row * 512);
  float4 v0 = yr[lane], v1 = yr[64 + lane];
  float4 b0 = ((const float4*)b_out)[lane], b1 = ((const float4*)b_out)[64 + lane];
  v0.x += b0.x; v0.y += b0.y; v0.z += b0.z; v0.w += b0.w;
  v1.x += b1.x; v1.y += b1.y; v1.z += b1.z; v1.w += b1.w;
  float s  = v0.x + v0.y + v0.z + v0.w + v1.x + v1.y + v1.z + v1.w;
  float s2 = v0.x * v0.x + v0.y * v0.y + v0.z * v0.z + v0.w * v0.w +
             v1.x * v1.x + v1.y * v1.y + v1.z * v1.z + v1.w * v1.w;
  for (int off = 32; off; off >>= 1) {
    s += __shfl_xor(s, off);
    s2 += __shfl_xor(s2, off);
  }
  float mean = s * (1.0f / 512.0f);
  float var = s2 * (1.0f / 512.0f) - mean * mean;
  float rs = rsqrtf(var + 1e-5f);
  float4 g0 = ((const float4*)gamma)[lane], g1 = ((const float4*)gamma)[64 + lane];
  float4 e0 = ((const float4*)beta)[lane], e1 = ((const float4*)beta)[64 + lane];
  float4 o0, o1;
  o0.x = (v0.x - mean) * rs * g0.x + e0.x;  o0.y = (v0.y - mean) * rs * g0.y + e0.y;
  o0.z = (v0.z - mean) * rs * g0.z + e0.z;  o0.w = (v0.w - mean) * rs * g0.w + e0.w;
  o1.x = (v1.x - mean) * rs * g1.x + e1.x;  o1.y = (v1.y - mean) * rs * g1.y + e1.y;
  o1.z = (v1.z - mean) * rs * g1.z + e1.z;  o1.w = (v1.w - mean) * rs * g1.w + e1.w;
  o0.x = o0.x >= 0.f ? o0.x : 0.1f * o0.x;  o0.y = o0.y >= 0.f ? o0.y : 0.1f * o0.y;
  o0.z = o0.z >= 0.f ? o0.z : 0.1f * o0.z;  o0.w = o0.w >= 0.f ? o0.w : 0.1f * o0.w;
  o1.x = o1.x >= 0.f ? o1.x : 0.1f * o1.x;  o1.y = o1.y >= 0.f ? o1.y : 0.1f * o1.y;
  o1.z = o1.z >= 0.f ? o1.z : 0.1f * o1.z;  o1.w = o1.w >= 0.f ? o1.w : 0.1f * o1.w;
  ((float4*)out)[(size_t)row * 128 + lane] = o0;
  ((float4*)out)[(size_t)row * 128 + 64 + lane] = o1;
}

// ---------------------------------------------------------------- launch
extern "C" void kernel_launch(void* const* d_in, const int* in_sizes, int n_in,
                              void* d_out, int out_size, void* d_ws, size_t ws_size,
                              hipStream_t stream) {
  const float* x      = (const float*)d_in[0];
  const float* wq     = (const float*)d_in[1];
  const float* wk     = (const float*)d_in[2];
  const float* wv     = (const float*)d_in[3];
  const float* w_out  = (const float*)d_in[4];
  const float* b_out  = (const float*)d_in[5];
  const float* gamma  = (const float*)d_in[6];
  const float* beta   = (const float*)d_in[7];
  float* out = (float*)d_out;

  char* ws = (char*)d_ws;
  size_t off = 0;
  u16* xb  = (u16*)(ws + off); off += (size_t)MROWS * INDIM * 2;        // 16.8 MB
  u16* W1T = (u16*)(ws + off); off += (size_t)3 * OUTDIM * INDIM * 2;   // 1.6 MB
  u16* W2T = (u16*)(ws + off); off += (size_t)OUTDIM * INDIM * 2;       // 0.5 MB
  u16* Qb  = (u16*)(ws + off); off += (size_t)HEADS * NBATCH * SDIM * DHEAD * 2;
  u16* Kb  = (u16*)(ws + off); off += (size_t)HEADS * NBATCH * SDIM * DHEAD * 2;
  u16* VTb = (u16*)(ws + off); off += (size_t)HEADS * NBATCH * SDIM * DHEAD * 2;
  u16* hc  = (u16*)(ws + off); off += (size_t)MROWS * OUTDIM * 2;       // 16.8 MB
  float* Yv = (float*)(ws + off);                                       // 33.5 MB

  prep_kernel<<<2048, 256, 0, stream>>>(x, wq, wk, wv, w_out, xb, W1T, W2T);
  gemm128<0><<<dim3(12, 128), 256, 0, stream>>>(xb, W1T, Qb, Kb, VTb, nullptr);
  attn_kernel<<<256, 512, 0, stream>>>(Qb, Kb, VTb, hc);
  gemm128<1><<<dim3(4, 128), 256, 0, stream>>>(hc, W2T, nullptr, nullptr, nullptr, Yv);
  ln_kernel<<<4096, 256, 0, stream>>>(Yv, b_out, gamma, beta, out);
}

// Round 2
// 399.569 us; speedup vs baseline: 1.1484x; 1.1484x over previous
//
#include <hip/hip_runtime.h>

typedef unsigned short u16;
typedef unsigned int uint;
typedef __attribute__((ext_vector_type(8))) short bf16x8;
typedef __attribute__((ext_vector_type(4))) float f32x4;

#define NBATCH 16
#define SDIM   1024
#define INDIM  512
#define OUTDIM 512
#define HEADS  8
#define DHEAD  64
#define MROWS  (NBATCH * SDIM)   // 16384
#define KDIM   512

__device__ __forceinline__ u16 f2bf(float f) {
  union { float f; uint u; } v; v.f = f;
  uint u = v.u;
  return (u16)((u + 0x7FFFu + ((u >> 16) & 1u)) >> 16);  // RNE
}

__device__ __forceinline__ void gload16(const void* g, void* l) {
  __builtin_amdgcn_global_load_lds(
      (const __attribute__((address_space(1))) uint*)g,
      (__attribute__((address_space(3))) uint*)l, 16, 0, 0);
}

// ---------------------------------------------------------------- prep
__global__ __launch_bounds__(256) void prep_kernel(
    const float* __restrict__ x, const float* __restrict__ wq,
    const float* __restrict__ wk, const float* __restrict__ wv,
    const float* __restrict__ w_out,
    u16* __restrict__ xb, u16* __restrict__ W1T, u16* __restrict__ W2T) {
  int gid = blockIdx.x * blockDim.x + threadIdx.x;
  int stride = gridDim.x * blockDim.x;
  const int NX4 = MROWS * INDIM / 4;
  for (int i = gid; i < NX4; i += stride) {
    float4 v = ((const float4*)x)[i];
    ((ushort4*)xb)[i] = make_ushort4(f2bf(v.x), f2bf(v.y), f2bf(v.z), f2bf(v.w));
  }
  // W1T[n][f], n = proj*512 + h*64 + d ; wq scaled by 1/sqrt(DH)=0.125 (exact)
  for (int i = gid; i < 3 * OUTDIM * INDIM; i += stride) {
    int n = i >> 9, f = i & 511;
    int proj = n >> 9, hd = n & 511, h = hd >> 6, d = hd & 63;
    const float* src = (proj == 0) ? wq : (proj == 1) ? wk : wv;
    float val = src[(h * INDIM + f) * DHEAD + d];
    if (proj == 0) val *= 0.125f;
    W1T[i] = f2bf(val);
  }
  // W2T[n][f] = w_out[f][n]
  for (int i = gid; i < OUTDIM * INDIM; i += stride) {
    int n = i >> 9, f = i & 511;
    W2T[i] = f2bf(w_out[f * OUTDIM + n]);
  }
}

// ---------------------------------------------------------------- GEMM 128x128, BK=32
template <int EPI>
__global__ __launch_bounds__(256) void gemm128(
    const u16* __restrict__ A, const u16* __restrict__ Bt,
    u16* __restrict__ Qb, u16* __restrict__ Kb, u16* __restrict__ VTb,
    float* __restrict__ Y) {
  __shared__ u16 As[128 * 32];
  __shared__ u16 Bs[128 * 32];
  const int tid = threadIdx.x;
  const int w = tid >> 6, lane = tid & 63;
  const int quad = lane >> 4, ln = lane & 15;
  const int wm = w >> 1, wn = w & 1;
  const int m0 = blockIdx.y * 128, n0 = blockIdx.x * 128;

  f32x4 zero4 = {0.f, 0.f, 0.f, 0.f};
  f32x4 acc[4][4];
  for (int i = 0; i < 4; i++)
    for (int j = 0; j < 4; j++) acc[i][j] = zero4;

  const char* Ag = (const char*)(A + (size_t)m0 * KDIM);
  const char* Bg = (const char*)(Bt + (size_t)n0 * KDIM);
  const int r0 = w * 16 + (lane >> 2);
  const int cb = (lane & 3) * 16;

  for (int kk = 0; kk < KDIM; kk += 32) {
    __syncthreads();
    gload16(Ag + (size_t)r0 * (KDIM * 2) + kk * 2 + cb, (char*)As + w * 1024);
    gload16(Ag + (size_t)(r0 + 64) * (KDIM * 2) + kk * 2 + cb, (char*)As + 4096 + w * 1024);
    gload16(Bg + (size_t)r0 * (KDIM * 2) + kk * 2 + cb, (char*)Bs + w * 1024);
    gload16(Bg + (size_t)(r0 + 64) * (KDIM * 2) + kk * 2 + cb, (char*)Bs + 4096 + w * 1024);
    __syncthreads();
    bf16x8 af[4], bfr[4];
    for (int mt = 0; mt < 4; mt++)
      af[mt] = *(const bf16x8*)&As[(wm * 64 + mt * 16 + ln) * 32 + quad * 8];
    for (int nt = 0; nt < 4; nt++)
      bfr[nt] = *(const bf16x8*)&Bs[(wn * 64 + nt * 16 + ln) * 32 + quad * 8];
    for (int mt = 0; mt < 4; mt++)
      for (int nt = 0; nt < 4; nt++)
        acc[mt][nt] = __builtin_amdgcn_mfma_f32_16x16x32_bf16(af[mt], bfr[nt], acc[mt][nt], 0, 0, 0);
  }

  for (int mt = 0; mt < 4; mt++) {
    int mbase = m0 + wm * 64 + mt * 16 + quad * 4;
    int b = mbase >> 10, sbase = mbase & 1023;
    for (int nt = 0; nt < 4; nt++) {
      f32x4 c = acc[mt][nt];
      int col = n0 + wn * 64 + nt * 16 + ln;
      if (EPI == 0) {
        int proj = n0 >> 9;
        int hd = col & 511, h = hd >> 6, d = hd & 63;
        if (proj == 2) {
          *(ushort4*)&VTb[((size_t)(h * 16 + b) * 64 + d) * 1024 + sbase] =
              make_ushort4(f2bf(c[0]), f2bf(c[1]), f2bf(c[2]), f2bf(c[3]));
        } else {
          u16* dst = (proj == 0) ? Qb : Kb;
          size_t base = ((size_t)(h * 16 + b) * 1024) * 64 + d;
          dst[base + (size_t)(sbase + 0) * 64] = f2bf(c[0]);
          dst[base + (size_t)(sbase + 1) * 64] = f2bf(c[1]);
          dst[base + (size_t)(sbase + 2) * 64] = f2bf(c[2]);
          dst[base + (size_t)(sbase + 3) * 64] = f2bf(c[3]);
        }
      } else {
        Y[(size_t)(mbase + 0) * OUTDIM + col] = c[0];
        Y[(size_t)(mbase + 1) * OUTDIM + col] = c[1];
        Y[(size_t)(mbase + 2) * OUTDIM + col] = c[2];
        Y[(size_t)(mbase + 3) * OUTDIM + col] = c[3];
      }
    }
  }
}

// ---------------------------------------------------------------- attention
// grid 512 = h (bid&7, head->XCD affinity) x 64 s-subtiles (16 s each).
// block 512 = 8 waves; wave w owns batches {2w, 2w+1}; softmax over the batch
// axis is exact: the block's 8 waves cover all 16 b; one LDS exchange + ONE
// barrier per t-chunk (parity double-buffered lds_sum; lds_p is wave-private
// so no second barrier). All K/V loads for a chunk are issued up-front into
// register arrays so their L2 latency overlaps the exp/softmax VALU work.
__global__ __launch_bounds__(512, 4) void attn_kernel(
    const u16* __restrict__ Qb, const u16* __restrict__ Kb,
    const u16* __restrict__ VTb, u16* __restrict__ hc) {
  __shared__ float lds_sum[2][8 * 16 * 36];  // [parity][wave][s16][36 pad]
  __shared__ u16 lds_p[8 * 2 * 16 * 40];     // [wave][bi][s16][40 t-pad]
  const int tid = threadIdx.x;
  const int w = tid >> 6, lane = tid & 63;
  const int quad = lane >> 4, ln = lane & 15;
  const int h = blockIdx.x & 7, ssub = blockIdx.x >> 3;
  const int s0 = ssub * 16;
  const int b0 = w * 2;

  f32x4 zero4 = {0.f, 0.f, 0.f, 0.f};

  // resident Q fragments (B-operand: B[k=d][n=s], lane: s=ln, d=quad*8+j)
  bf16x8 qf[2][2];
  for (int bi = 0; bi < 2; bi++) {
    const u16* Qp = Qb + ((size_t)(h * 16 + b0 + bi) * 1024 + s0 + ln) * 64;
    qf[bi][0] = *(const bf16x8*)&Qp[quad * 8];
    qf[bi][1] = *(const bf16x8*)&Qp[32 + quad * 8];
  }
  const u16* Kp[2] = {Kb + (size_t)(h * 16 + b0) * 65536,
                      Kb + (size_t)(h * 16 + b0 + 1) * 65536};
  const u16* Vp[2] = {VTb + (size_t)(h * 16 + b0) * 65536,
                      VTb + (size_t)(h * 16 + b0 + 1) * 65536};

  f32x4 o[2][4];
  for (int i = 0; i < 2; i++)
    for (int j = 0; j < 4; j++) o[i][j] = zero4;

  for (int it = 0; it < 32; it++) {
    const int t0g = it * 32;
    // ---- issue ALL K loads (8 x 16B), then ALL V loads (8 x 16B) ----
    bf16x8 kf[2][2][2];
    for (int bi = 0; bi < 2; bi++)
      for (int tsub = 0; tsub < 2; tsub++) {
        const u16* Krow = Kp[bi] + (size_t)(t0g + tsub * 16 + ln) * 64;
        kf[bi][tsub][0] = *(const bf16x8*)&Krow[quad * 8];
        kf[bi][tsub][1] = *(const bf16x8*)&Krow[32 + quad * 8];
      }
    bf16x8 vf[2][4];
    for (int bi = 0; bi < 2; bi++)
      for (int df = 0; df < 4; df++)
        vf[bi][df] = *(const bf16x8*)&Vp[bi][(size_t)(df * 16 + ln) * 1024 + t0g + quad * 8];

    // ---- QK^T (transposed: row=t, col=s) + exp ----
    f32x4 e[2][2];
    for (int bi = 0; bi < 2; bi++)
      for (int tsub = 0; tsub < 2; tsub++) {
        f32x4 c = zero4;
        c = __builtin_amdgcn_mfma_f32_16x16x32_bf16(kf[bi][tsub][0], qf[bi][0], c, 0, 0, 0);
        c = __builtin_amdgcn_mfma_f32_16x16x32_bf16(kf[bi][tsub][1], qf[bi][1], c, 0, 0, 0);
        f32x4 ee;
        ee[0] = __expf(c[0]); ee[1] = __expf(c[1]);
        ee[2] = __expf(c[2]); ee[3] = __expf(c[3]);
        e[bi][tsub] = ee;
      }
    // ---- cross-batch softmax sum: 8-wave LDS exchange, ONE barrier ----
    f32x4 ls0 = e[0][0] + e[1][0];
    f32x4 ls1 = e[0][1] + e[1][1];
    {
      float* sb = &lds_sum[it & 1][(w * 16 + ln) * 36];
      *(f32x4*)&sb[quad * 4] = ls0;
      *(f32x4*)&sb[16 + quad * 4] = ls1;
    }
    __syncthreads();
    f32x4 L0 = zero4, L1 = zero4;
    for (int ob = 0; ob < 8; ob++) {
      const float* rb = &lds_sum[it & 1][(ob * 16 + ln) * 36];
      L0 += *(const f32x4*)&rb[quad * 4];
      L1 += *(const f32x4*)&rb[16 + quad * 4];
    }
    f32x4 R0, R1;
    for (int r = 0; r < 4; r++) {
      R0[r] = __builtin_amdgcn_rcpf(L0[r]);
      R1[r] = __builtin_amdgcn_rcpf(L1[r]);
    }
    // ---- P -> bf16 -> wave-private LDS (A-operand layout), no barrier ----
    for (int bi = 0; bi < 2; bi++) {
      f32x4 p0 = e[bi][0] * R0;
      f32x4 p1 = e[bi][1] * R1;
      u16* pb = &lds_p[((w * 2 + bi) * 16 + ln) * 40];
      *(ushort4*)&pb[quad * 4] = make_ushort4(f2bf(p0[0]), f2bf(p0[1]), f2bf(p0[2]), f2bf(p0[3]));
      *(ushort4*)&pb[16 + quad * 4] = make_ushort4(f2bf(p1[0]), f2bf(p1[1]), f2bf(p1[2]), f2bf(p1[3]));
    }
    // ---- PV ----
    for (int bi = 0; bi < 2; bi++) {
      bf16x8 pa = *(const bf16x8*)&lds_p[((w * 2 + bi) * 16 + ln) * 40 + quad * 8];
      for (int df = 0; df < 4; df++)
        o[bi][df] = __builtin_amdgcn_mfma_f32_16x16x32_bf16(pa, vf[bi][df], o[bi][df], 0, 0, 0);
    }
  }
  // epilogue: heads_cat [b*1024+s][h*64+d] bf16
  for (int bi = 0; bi < 2; bi++) {
    int b = b0 + bi;
    for (int df = 0; df < 4; df++) {
      f32x4 c = o[bi][df];
      for (int r = 0; r < 4; r++) {
        int sg = s0 + quad * 4 + r;
        hc[((size_t)(b * 1024 + sg)) * 512 + h * 64 + df * 16 + ln] = f2bf(c[r]);
      }
    }
  }
}

// ---------------------------------------------------------------- bias + LN + LeakyReLU
__global__ __launch_bounds__(256) void ln_kernel(
    const float* __restrict__ Y, const float* __restrict__ b_out,
    const float* __restrict__ gamma, const float* __restrict__ beta,
    float* __restrict__ out) {
  const int w = threadIdx.x >> 6, lane = threadIdx.x & 63;
  const int row = blockIdx.x * 4 + w;
  const float4* yr = (const float4*)(Y + (size_t)row * 512);
  float4 v0 = yr[lane], v1 = yr[64 + lane];
  float4 b0 = ((const float4*)b_out)[lane], b1 = ((const float4*)b_out)[64 + lane];
  v0.x += b0.x; v0.y += b0.y; v0.z += b0.z; v0.w += b0.w;
  v1.x += b1.x; v1.y += b1.y; v1.z += b1.z; v1.w += b1.w;
  float s  = v0.x + v0.y + v0.z + v0.w + v1.x + v1.y + v1.z + v1.w;
  float s2 = v0.x * v0.x + v0.y * v0.y + v0.z * v0.z + v0.w * v0.w +
             v1.x * v1.x + v1.y * v1.y + v1.z * v1.z + v1.w * v1.w;
  for (int off = 32; off; off >>= 1) {
    s += __shfl_xor(s, off);
    s2 += __shfl_xor(s2, off);
  }
  float mean = s * (1.0f / 512.0f);
  float var = s2 * (1.0f / 512.0f) - mean * mean;
  float rs = rsqrtf(var + 1e-5f);
  float4 g0 = ((const float4*)gamma)[lane], g1 = ((const float4*)gamma)[64 + lane];
  float4 e0 = ((const float4*)beta)[lane], e1 = ((const float4*)beta)[64 + lane];
  float4 o0, o1;
  o0.x = (v0.x - mean) * rs * g0.x + e0.x;  o0.y = (v0.y - mean) * rs * g0.y + e0.y;
  o0.z = (v0.z - mean) * rs * g0.z + e0.z;  o0.w = (v0.w - mean) * rs * g0.w + e0.w;
  o1.x = (v1.x - mean) * rs * g1.x + e1.x;  o1.y = (v1.y - mean) * rs * g1.y + e1.y;
  o1.z = (v1.z - mean) * rs * g1.z + e1.z;  o1.w = (v1.w - mean) * rs * g1.w + e1.w;
  o0.x = o0.x >= 0.f ? o0.x : 0.1f * o0.x;  o0.y = o0.y >= 0.f ? o0.y : 0.1f * o0.y;
  o0.z = o0.z >= 0.f ? o0.z : 0.1f * o0.z;  o0.w = o0.w >= 0.f ? o0.w : 0.1f * o0.w;
  o1.x = o1.x >= 0.f ? o1.x : 0.1f * o1.x;  o1.y = o1.y >= 0.f ? o1.y : 0.1f * o1.y;
  o1.z = o1.z >= 0.f ? o1.z : 0.1f * o1.z;  o1.w = o1.w >= 0.f ? o1.w : 0.1f * o1.w;
  ((float4*)out)[(size_t)row * 128 + lane] = o0;
  ((float4*)out)[(size_t)row * 128 + 64 + lane] = o1;
}

// ---------------------------------------------------------------- launch
extern "C" void kernel_launch(void* const* d_in, const int* in_sizes, int n_in,
                              void* d_out, int out_size, void* d_ws, size_t ws_size,
                              hipStream_t stream) {
  const float* x      = (const float*)d_in[0];
  const float* wq     = (const float*)d_in[1];
  const float* wk     = (const float*)d_in[2];
  const float* wv     = (const float*)d_in[3];
  const float* w_out  = (const float*)d_in[4];
  const float* b_out  = (const float*)d_in[5];
  const float* gamma  = (const float*)d_in[6];
  const float* beta   = (const float*)d_in[7];
  float* out = (float*)d_out;

  char* ws = (char*)d_ws;
  size_t off = 0;
  u16* xb  = (u16*)(ws + off); off += (size_t)MROWS * INDIM * 2;
  u16* W1T = (u16*)(ws + off); off += (size_t)3 * OUTDIM * INDIM * 2;
  u16* W2T = (u16*)(ws + off); off += (size_t)OUTDIM * INDIM * 2;
  u16* Qb  = (u16*)(ws + off); off += (size_t)HEADS * NBATCH * SDIM * DHEAD * 2;
  u16* Kb  = (u16*)(ws + off); off += (size_t)HEADS * NBATCH * SDIM * DHEAD * 2;
  u16* VTb = (u16*)(ws + off); off += (size_t)HEADS * NBATCH * SDIM * DHEAD * 2;
  u16* hc  = (u16*)(ws + off); off += (size_t)MROWS * OUTDIM * 2;
  float* Yv = (float*)(ws + off);

  prep_kernel<<<2048, 256, 0, stream>>>(x, wq, wk, wv, w_out, xb, W1T, W2T);
  gemm128<0><<<dim3(12, 128), 256, 0, stream>>>(xb, W1T, Qb, Kb, VTb, nullptr);
  attn_kernel<<<512, 512, 0, stream>>>(Qb, Kb, VTb, hc);
  gemm128<1><<<dim3(4, 128), 256, 0, stream>>>(hc, W2T, nullptr, nullptr, nullptr, Yv);
  ln_kernel<<<4096, 256, 0, stream>>>(Yv, b_out, gamma, beta, out);
}